// Round 14
// baseline (307.472 us; speedup 1.0000x reference)
//
#include <hip/hip_runtime.h>

#define V_N 12288
#define B_N 16
#define TF_N 256          // T*Fin
#define ROW2 1024         // B_N * FOUT  (clenshaw row elems)
#define FOUT 64
#define TPB_TILES 4       // tiles (vb,b) per block in k_proj

typedef __attribute__((ext_vector_type(8))) short short8;
typedef __attribute__((ext_vector_type(4))) float f32x4;

__device__ __forceinline__ unsigned short f2bf(float x){
  unsigned u = __float_as_uint(x);
  return (unsigned short)((u + 0x7FFFu + ((u >> 16) & 1u)) >> 16);
}
__device__ __forceinline__ float bf2f(unsigned short h){
  return __uint_as_float(((unsigned)h) << 16);
}

__global__ void k_zero(int* __restrict__ p, int n){
  int i = blockIdx.x * 256 + threadIdx.x;
  if (i < n) p[i] = 0;
}

__global__ void k_hist(const int* __restrict__ rows, int* __restrict__ cnt, int nnz){
  int i = blockIdx.x * 256 + threadIdx.x;
  if (i < nnz) atomicAdd(&cnt[rows[i]], 1);
}

__global__ void k_scan(const int* __restrict__ cnt, int* __restrict__ rp){
  __shared__ int part[256];
  __shared__ int base[257];
  int t = threadIdx.x;
  const int per = V_N / 256;   // 48 = 12 x int4
  int4 c[12];
  #pragma unroll
  for (int i = 0; i < 12; ++i) c[i] = *(const int4*)(cnt + t * per + i * 4);
  int s = 0;
  #pragma unroll
  for (int i = 0; i < 12; ++i) s += c[i].x + c[i].y + c[i].z + c[i].w;
  part[t] = s;
  __syncthreads();
  if (t == 0){
    int run = 0;
    for (int i = 0; i < 256; ++i){ base[i] = run; run += part[i]; }
    base[256] = run;
  }
  __syncthreads();
  int run = base[t];
  #pragma unroll
  for (int i = 0; i < 12; ++i){
    int4 o;
    o.x = run; run += c[i].x;
    o.y = run; run += c[i].y;
    o.z = run; run += c[i].z;
    o.w = run; run += c[i].w;
    *(int4*)(rp + t * per + i * 4) = o;
  }
  if (t == 255) rp[V_N] = run;
}

__global__ void k_scatter(const int* __restrict__ rows, const int* __restrict__ cols,
                          const float* __restrict__ vals, const int* __restrict__ rp,
                          int* __restrict__ cur, int* __restrict__ cols_s,
                          float* __restrict__ vals_s, int nnz){
  int i = blockIdx.x * 256 + threadIdx.x;
  if (i < nnz){
    int r = rows[i];
    int pos = rp[r] + atomicAdd(&cur[r], 1);
    cols_s[pos] = cols[i];
    vals_s[pos] = vals[i];
  }
}

// weight [Fin=64][Kv=4][Kt=4][Fout=64] f32 -> wb fragment-ordered
// wb[i], i = (((k*8 + s)*4 + n)*64 + lane)*8 + j
// holds W[f,k,t,o] with kk = s*32 + (lane>>4)*8 + j, t=kk>>6, f=kk&63, o=n*16+(lane&15)
__global__ void k_convw(const float* __restrict__ w, unsigned short* __restrict__ wb){
  int i = blockIdx.x * 256 + threadIdx.x;   // 65536 threads
  int j = i & 7;
  int l = (i >> 3) & 63;
  int n = (i >> 9) & 3;
  int s = (i >> 11) & 7;
  int k = (i >> 14) & 3;
  int kk = s * 32 + ((l >> 4) << 3) + j;
  int t = kk >> 6, f = kk & 63;
  int o = (n << 4) + (l & 15);
  wb[i] = f2bf(w[((f * 4 + k) * 4 + t) * 64 + o]);
}

// y_k[v][b*64 + colL*4 + n] = (X0 @ W_k)[v, b, o=n*16+colL]   (PERMUTED row layout)
// OCCUPANCY-DOUBLED proj: 512-thread blocks (8 waves); wave w owns
// (k = w&3, n-half = w>>2) -> W shrinks to short8[8][2] = 64 VGPR and staging
// to 4 x float4/thread. Total ~120 VGPR <= 128 boundary -> 4 waves/SIMD
// (enforced by __launch_bounds__(512,4)); R3 showed occupancy-without-reg-W
// loses (L2 traffic), R7 showed reg-W-without-occupancy is latency-bound at
// 2 waves/SIMD; this keeps W in regs AND doubles waves. Same MFMA count,
// same A-tile traffic, same per-output summation order.
__global__ __launch_bounds__(512, 4) void k_proj(
                       const float* __restrict__ in, const unsigned short* __restrict__ wb,
                       unsigned short* __restrict__ y0, unsigned short* __restrict__ y1,
                       unsigned short* __restrict__ y2, unsigned short* __restrict__ y3){
  __shared__ unsigned short As[2][32 * 256];   // 2 x 16 KB
  int t = threadIdx.x;
  int lane = t & 63;
  int w    = t >> 6;          // 0..7
  int k    = w & 3;
  int nh   = w >> 2;          // n-half: n = nh*2 + m, m in {0,1}
  int colL = lane & 15, rg = lane >> 4;

  int tile0 = blockIdx.x * TPB_TILES;    // flat tile = vb*16 + b

  // issue first tile's staging loads ASAP (16 floats = 4 float4 per thread)
  float4 r[4];
  {
    int vb = tile0 >> 4, b = tile0 & 15;
    const float* src = in + ((size_t)b * V_N + vb * 32) * TF_N;
    #pragma unroll
    for (int i = 0; i < 4; ++i) r[i] = *(const float4*)(src + i * 2048 + t * 4);
  }

  // persistent W fragments for this wave's (k, nh) (statically indexed)
  short8 W[8][2];
  {
    const unsigned short* wk = wb + k * 16384 + lane * 8;
    #pragma unroll
    for (int s = 0; s < 8; ++s)
      #pragma unroll
      for (int m = 0; m < 2; ++m)
        W[s][m] = *(const short8*)(wk + ((s * 4 + nh * 2 + m) << 9));
  }
  unsigned short* yk = (k == 0) ? y0 : (k == 1) ? y1 : (k == 2) ? y2 : y3;

  #pragma unroll
  for (int ti = 0; ti < TPB_TILES; ++ti){
    int ft = tile0 + ti;
    char* lds = (char*)As[ti & 1];
    // stage current tile (waits on r's loads), then issue next tile's loads
    #pragma unroll
    for (int i = 0; i < 4; ++i){
      int flat = i * 2048 + t * 4;
      int row = flat >> 8;
      int c2  = (flat & 255) * 2;
      unsigned long long pk =  (unsigned long long)f2bf(r[i].x)
                            | ((unsigned long long)f2bf(r[i].y) << 16)
                            | ((unsigned long long)f2bf(r[i].z) << 32)
                            | ((unsigned long long)f2bf(r[i].w) << 48);
      *(unsigned long long*)(lds + ((row * 512 + c2) ^ ((row & 7) << 4))) = pk;
    }
    if (ti + 1 < TPB_TILES){
      int ft1 = ft + 1;
      int vb = ft1 >> 4, b = ft1 & 15;
      const float* src = in + ((size_t)b * V_N + vb * 32) * TF_N;
      #pragma unroll
      for (int i = 0; i < 4; ++i) r[i] = *(const float4*)(src + i * 2048 + t * 4);
    }
    __syncthreads();

    f32x4 acc[2][2];
    #pragma unroll
    for (int mt = 0; mt < 2; ++mt)
      #pragma unroll
      for (int m = 0; m < 2; ++m) acc[mt][m] = (f32x4){0.f, 0.f, 0.f, 0.f};

    #pragma unroll
    for (int s = 0; s < 8; ++s){
      int c2 = rg * 16 + s * 64;
      short8 a0 = *(const short8*)(lds + (( colL       * 512 + c2) ^ ((colL & 7) << 4)));
      short8 a1 = *(const short8*)(lds + (((16 + colL) * 512 + c2) ^ ((colL & 7) << 4)));
      #pragma unroll
      for (int m = 0; m < 2; ++m){
        acc[0][m] = __builtin_amdgcn_mfma_f32_16x16x32_bf16(a0, W[s][m], acc[0][m], 0, 0, 0);
        acc[1][m] = __builtin_amdgcn_mfma_f32_16x16x32_bf16(a1, W[s][m], acc[1][m], 0, 0, 0);
      }
    }
    // packed store: lane's 2 n-values -> 4 bytes at [v][b*64 + colL*4 + nh*2]
    {
      int vb = ft >> 4, b = ft & 15, v0 = vb * 32;
      #pragma unroll
      for (int mt = 0; mt < 2; ++mt)
        #pragma unroll
        for (int q = 0; q < 4; ++q){
          int v = v0 + mt * 16 + rg * 4 + q;
          unsigned pk = (unsigned)f2bf(acc[mt][0][q]) | ((unsigned)f2bf(acc[mt][1][q]) << 16);
          *(unsigned*)(yk + (size_t)v * ROW2 + b * 64 + colL * 4 + nh * 2) = pk;
        }
    }
    __syncthreads();
  }
}

// dst[r] = alpha * (L @ src)[r] + addA[r] - (subB ? subB[r] : 0)    rows of 1024 bf16
// Sequential gather (one row at a time) — measured-best of {batched (R6),
// j-split (R8), XCD-sliced (R9)}. TLP covers the gather latency; effective
// gather throughput ~6.8 TB/s aggregate (L3/HBM ceiling).
__global__ void k_spmm2(const unsigned short* __restrict__ src,
                        const unsigned short* __restrict__ addA,
                        const unsigned short* __restrict__ subB,
                        unsigned short* __restrict__ dst,
                        const int* __restrict__ rp, const int* __restrict__ cols,
                        const float* __restrict__ vals, float alpha){
  int lane = threadIdx.x & 63;
  int r = blockIdx.x * 4 + (threadIdx.x >> 6);
  int j0 = lane * 16;
  float acc[16];
  #pragma unroll
  for (int p = 0; p < 16; ++p) acc[p] = 0.f;
  int beg = rp[r], end = rp[r + 1];
  for (int i = beg; i < end; ++i){
    float val = vals[i];
    int c = cols[i];
    const unsigned short* srow = src + (size_t)c * ROW2 + j0;
    short8 a0 = *(const short8*)srow;
    short8 a1 = *(const short8*)(srow + 8);
    #pragma unroll
    for (int p = 0; p < 8; ++p) acc[p]     += val * bf2f((unsigned short)a0[p]);
    #pragma unroll
    for (int p = 0; p < 8; ++p) acc[p + 8] += val * bf2f((unsigned short)a1[p]);
  }
  const unsigned short* arow = addA + (size_t)r * ROW2 + j0;
  short8 q0 = *(const short8*)arow;
  short8 q1 = *(const short8*)(arow + 8);
  #pragma unroll
  for (int p = 0; p < 8; ++p) acc[p]     = alpha * acc[p]     + bf2f((unsigned short)q0[p]);
  #pragma unroll
  for (int p = 0; p < 8; ++p) acc[p + 8] = alpha * acc[p + 8] + bf2f((unsigned short)q1[p]);
  if (subB){
    const unsigned short* brow = subB + (size_t)r * ROW2 + j0;
    short8 s0 = *(const short8*)brow;
    short8 s1 = *(const short8*)(brow + 8);
    #pragma unroll
    for (int p = 0; p < 8; ++p) acc[p]     -= bf2f((unsigned short)s0[p]);
    #pragma unroll
    for (int p = 0; p < 8; ++p) acc[p + 8] -= bf2f((unsigned short)s1[p]);
  }
  unsigned short* drow = dst + (size_t)r * ROW2 + j0;
  short8 o0, o1;
  #pragma unroll
  for (int p = 0; p < 8; ++p) o0[p] = (short)f2bf(acc[p]);
  #pragma unroll
  for (int p = 0; p < 8; ++p) o1[p] = (short)f2bf(acc[p + 8]);
  *(short8*)drow = o0;
  *(short8*)(drow + 8) = o1;
}

// out[b][v][o] = (L @ b1)[v][j] + y0[v][j] - b2[v][j] + bias[o]
// row layout: j = b*64 + colL*4 + n  <->  o = n*16 + colL  (un-permute on store)
__global__ void k_final(const unsigned short* __restrict__ src,   // b1
                        const unsigned short* __restrict__ y0,
                        const unsigned short* __restrict__ b2,
                        const float* __restrict__ bias,
                        float* __restrict__ out,
                        const int* __restrict__ rp, const int* __restrict__ cols,
                        const float* __restrict__ vals){
  int lane = threadIdx.x & 63;
  int v = blockIdx.x * 4 + (threadIdx.x >> 6);
  int j0 = lane * 16;
  float acc[16];
  #pragma unroll
  for (int p = 0; p < 16; ++p) acc[p] = 0.f;
  int beg = rp[v], end = rp[v + 1];
  for (int i = beg; i < end; ++i){
    float val = vals[i];
    int c = cols[i];
    const unsigned short* srow = src + (size_t)c * ROW2 + j0;
    short8 a0 = *(const short8*)srow;
    short8 a1 = *(const short8*)(srow + 8);
    #pragma unroll
    for (int p = 0; p < 8; ++p) acc[p]     += val * bf2f((unsigned short)a0[p]);
    #pragma unroll
    for (int p = 0; p < 8; ++p) acc[p + 8] += val * bf2f((unsigned short)a1[p]);
  }
  const unsigned short* yrow = y0 + (size_t)v * ROW2 + j0;
  const unsigned short* brow = b2 + (size_t)v * ROW2 + j0;
  short8 q0 = *(const short8*)yrow;
  short8 q1 = *(const short8*)(yrow + 8);
  short8 s0 = *(const short8*)brow;
  short8 s1 = *(const short8*)(brow + 8);
  #pragma unroll
  for (int p = 0; p < 8; ++p) acc[p]     += bf2f((unsigned short)q0[p]) - bf2f((unsigned short)s0[p]);
  #pragma unroll
  for (int p = 0; p < 8; ++p) acc[p + 8] += bf2f((unsigned short)q1[p]) - bf2f((unsigned short)s1[p]);
  // j = j0+p ; b = lane>>2 ; c0 = (lane&3)*4 ; p = q*4+n -> o = n*16 + c0 + q
  int b = lane >> 2;
  int c0 = (lane & 3) * 4;
  float* obase = out + ((size_t)b * V_N + v) * FOUT;
  #pragma unroll
  for (int n = 0; n < 4; ++n){
    float4 bv = *(const float4*)(bias + n * 16 + c0);
    float4 w;
    w.x = acc[0 * 4 + n] + bv.x;
    w.y = acc[1 * 4 + n] + bv.y;
    w.z = acc[2 * 4 + n] + bv.z;
    w.w = acc[3 * 4 + n] + bv.w;
    *(float4*)(obase + n * 16 + c0) = w;
  }
}

extern "C" void kernel_launch(void* const* d_in, const int* in_sizes, int n_in,
                              void* d_out, int out_size, void* d_ws, size_t ws_size,
                              hipStream_t stream) {
  const float* inputs   = (const float*)d_in[0];
  const float* weight   = (const float*)d_in[1];
  const float* bias     = (const float*)d_in[2];
  const float* lap_vals = (const float*)d_in[3];
  const int*   lap_rows = (const int*)d_in[4];
  const int*   lap_cols = (const int*)d_in[5];
  float* out = (float*)d_out;
  int nnz = in_sizes[3];

  char* ws = (char*)d_ws;
  size_t off = 0;
  auto alloc = [&](size_t bytes) -> void* {
    void* p = ws + off;
    off += (bytes + 255) & ~(size_t)255;
    return p;
  };
  const size_t YB = (size_t)V_N * ROW2 * 2;   // 24 MiB
  unsigned short* y0 = (unsigned short*)alloc(YB);
  unsigned short* y1 = (unsigned short*)alloc(YB);
  unsigned short* y2 = (unsigned short*)alloc(YB);
  unsigned short* y3 = (unsigned short*)alloc(YB);
  unsigned short* c2 = (unsigned short*)alloc(YB);   // clenshaw b2
  unsigned short* c1 = (unsigned short*)alloc(YB);   // clenshaw b1
  unsigned short* wb = (unsigned short*)alloc(65536 * 2);
  int*   cnt   = (int*)alloc(V_N * 4);
  int*   cur   = (int*)alloc(V_N * 4);
  int*   rp    = (int*)alloc((V_N + 1) * 4);
  int*   colss = (int*)alloc((size_t)nnz * 4);
  float* valss = (float*)alloc((size_t)nnz * 4);

  // CSR build
  k_zero<<<(2 * V_N + 255) / 256, 256, 0, stream>>>(cnt, 2 * V_N);
  k_hist<<<(nnz + 255) / 256, 256, 0, stream>>>(lap_rows, cnt, nnz);
  k_scan<<<1, 256, 0, stream>>>(cnt, rp);
  k_scatter<<<(nnz + 255) / 256, 256, 0, stream>>>(lap_rows, lap_cols, lap_vals, rp, cur,
                                                   colss, valss, nnz);
  // weight fragments + projection y_k = X0 @ W_k
  k_convw<<<65536 / 256, 256, 0, stream>>>(weight, wb);
  k_proj<<<(V_N / 32) * B_N / TPB_TILES, 512, 0, stream>>>(inputs, wb, y0, y1, y2, y3);

  // Clenshaw: b2 = y2 + 2 L y3 ; b1 = y1 + 2 L b2 - y3 ; out = y0 + L b1 - b2 + bias
  k_spmm2<<<V_N / 4, 256, 0, stream>>>(y3, y2, nullptr, c2, rp, colss, valss, 2.0f);
  k_spmm2<<<V_N / 4, 256, 0, stream>>>(c2, y1, y3, c1, rp, colss, valss, 2.0f);
  k_final<<<V_N / 4, 256, 0, stream>>>(c1, y0, c2, bias, out, rp, colss, valss);
}

// Round 15
// 213.432 us; speedup vs baseline: 1.4406x; 1.4406x over previous
//
#include <hip/hip_runtime.h>

#define V_N 12288
#define B_N 16
#define TF_N 256          // T*Fin
#define ROW2 1024         // B_N * FOUT  (clenshaw row elems)
#define FOUT 64
#define TPB_TILES 4       // tiles (vb,b) per block in k_proj

typedef __attribute__((ext_vector_type(8))) short short8;
typedef __attribute__((ext_vector_type(4))) float f32x4;

__device__ __forceinline__ unsigned short f2bf(float x){
  unsigned u = __float_as_uint(x);
  return (unsigned short)((u + 0x7FFFu + ((u >> 16) & 1u)) >> 16);
}
__device__ __forceinline__ float bf2f(unsigned short h){
  return __uint_as_float(((unsigned)h) << 16);
}

__global__ void k_zero(int* __restrict__ p, int n){
  int i = blockIdx.x * 256 + threadIdx.x;
  if (i < n) p[i] = 0;
}

__global__ void k_hist(const int* __restrict__ rows, int* __restrict__ cnt, int nnz){
  int i = blockIdx.x * 256 + threadIdx.x;
  if (i < nnz) atomicAdd(&cnt[rows[i]], 1);
}

__global__ void k_scan(const int* __restrict__ cnt, int* __restrict__ rp){
  __shared__ int part[256];
  __shared__ int base[257];
  int t = threadIdx.x;
  const int per = V_N / 256;   // 48 = 12 x int4
  int4 c[12];
  #pragma unroll
  for (int i = 0; i < 12; ++i) c[i] = *(const int4*)(cnt + t * per + i * 4);
  int s = 0;
  #pragma unroll
  for (int i = 0; i < 12; ++i) s += c[i].x + c[i].y + c[i].z + c[i].w;
  part[t] = s;
  __syncthreads();
  if (t == 0){
    int run = 0;
    for (int i = 0; i < 256; ++i){ base[i] = run; run += part[i]; }
    base[256] = run;
  }
  __syncthreads();
  int run = base[t];
  #pragma unroll
  for (int i = 0; i < 12; ++i){
    int4 o;
    o.x = run; run += c[i].x;
    o.y = run; run += c[i].y;
    o.z = run; run += c[i].z;
    o.w = run; run += c[i].w;
    *(int4*)(rp + t * per + i * 4) = o;
  }
  if (t == 255) rp[V_N] = run;
}

__global__ void k_scatter(const int* __restrict__ rows, const int* __restrict__ cols,
                          const float* __restrict__ vals, const int* __restrict__ rp,
                          int* __restrict__ cur, int* __restrict__ cols_s,
                          float* __restrict__ vals_s, int nnz){
  int i = blockIdx.x * 256 + threadIdx.x;
  if (i < nnz){
    int r = rows[i];
    int pos = rp[r] + atomicAdd(&cur[r], 1);
    cols_s[pos] = cols[i];
    vals_s[pos] = vals[i];
  }
}

// weight [Fin=64][Kv=4][Kt=4][Fout=64] f32 -> wb fragment-ordered
// wb[i], i = (((k*8 + s)*4 + n)*64 + lane)*8 + j
// holds W[f,k,t,o] with kk = s*32 + (lane>>4)*8 + j, t=kk>>6, f=kk&63, o=n*16+(lane&15)
__global__ void k_convw(const float* __restrict__ w, unsigned short* __restrict__ wb){
  int i = blockIdx.x * 256 + threadIdx.x;   // 65536 threads
  int j = i & 7;
  int l = (i >> 3) & 63;
  int n = (i >> 9) & 3;
  int s = (i >> 11) & 7;
  int k = (i >> 14) & 3;
  int kk = s * 32 + ((l >> 4) << 3) + j;
  int t = kk >> 6, f = kk & 63;
  int o = (n << 4) + (l & 15);
  wb[i] = f2bf(w[((f * 4 + k) * 4 + t) * 64 + o]);
}

// y_k[v][b*64 + colL*4 + n] = (X0 @ W_k)[v, b, o=n*16+colL]   (PERMUTED row layout)
// SESSION-BEST proj (R12, 213.5us total): W_k register-persistent per wave
// (128 VGPR, 2 blocks/CU); A tiles staged regs -> bf16 XOR-swizzled LDS,
// double-buffered; next tile's global loads issued before the barrier.
// Measured-closed alternatives: W-from-L2 (117us), f32-LDS+global_load_lds
// (regress), 3-buffer deep pipeline (null/regress), post-barrier prefetch
// (null), 512-thr/64-VGPR-W occupancy split (spills, 159us).
__global__ __launch_bounds__(256, 2) void k_proj(
                       const float* __restrict__ in, const unsigned short* __restrict__ wb,
                       unsigned short* __restrict__ y0, unsigned short* __restrict__ y1,
                       unsigned short* __restrict__ y2, unsigned short* __restrict__ y3){
  __shared__ unsigned short As[2][32 * 256];   // 2 x 16 KB
  int t = threadIdx.x;
  int lane = t & 63;
  int k    = t >> 6;
  int colL = lane & 15, rg = lane >> 4;

  int tile0 = blockIdx.x * TPB_TILES;    // flat tile = vb*16 + b

  // issue first tile's staging loads ASAP
  float4 r[8];
  {
    int vb = tile0 >> 4, b = tile0 & 15;
    const float* src = in + ((size_t)b * V_N + vb * 32) * TF_N;
    #pragma unroll
    for (int i = 0; i < 8; ++i) r[i] = *(const float4*)(src + i * 1024 + t * 4);
  }

  // persistent W fragments for this wave's k (statically indexed)
  short8 W[8][4];
  {
    const unsigned short* wk = wb + k * 16384 + lane * 8;
    #pragma unroll
    for (int s = 0; s < 8; ++s)
      #pragma unroll
      for (int n = 0; n < 4; ++n)
        W[s][n] = *(const short8*)(wk + ((s * 4 + n) << 9));
  }
  unsigned short* yk = (k == 0) ? y0 : (k == 1) ? y1 : (k == 2) ? y2 : y3;

  #pragma unroll
  for (int ti = 0; ti < TPB_TILES; ++ti){
    int ft = tile0 + ti;
    char* lds = (char*)As[ti & 1];
    // write staged tile (waits on r's loads), then issue next tile's loads
    #pragma unroll
    for (int i = 0; i < 8; ++i){
      int flat = i * 1024 + t * 4;
      int row = flat >> 8;
      int c2  = (flat & 255) * 2;
      unsigned long long pk =  (unsigned long long)f2bf(r[i].x)
                            | ((unsigned long long)f2bf(r[i].y) << 16)
                            | ((unsigned long long)f2bf(r[i].z) << 32)
                            | ((unsigned long long)f2bf(r[i].w) << 48);
      *(unsigned long long*)(lds + ((row * 512 + c2) ^ ((row & 7) << 4))) = pk;
    }
    if (ti + 1 < TPB_TILES){
      int ft1 = ft + 1;
      int vb = ft1 >> 4, b = ft1 & 15;
      const float* src = in + ((size_t)b * V_N + vb * 32) * TF_N;
      #pragma unroll
      for (int i = 0; i < 8; ++i) r[i] = *(const float4*)(src + i * 1024 + t * 4);
    }
    __syncthreads();

    f32x4 acc[2][4];
    #pragma unroll
    for (int mt = 0; mt < 2; ++mt)
      #pragma unroll
      for (int n = 0; n < 4; ++n) acc[mt][n] = (f32x4){0.f, 0.f, 0.f, 0.f};

    #pragma unroll
    for (int s = 0; s < 8; ++s){
      int c2 = rg * 16 + s * 64;
      short8 a0 = *(const short8*)(lds + (( colL       * 512 + c2) ^ ((colL & 7) << 4)));
      short8 a1 = *(const short8*)(lds + (((16 + colL) * 512 + c2) ^ ((colL & 7) << 4)));
      #pragma unroll
      for (int n = 0; n < 4; ++n){
        acc[0][n] = __builtin_amdgcn_mfma_f32_16x16x32_bf16(a0, W[s][n], acc[0][n], 0, 0, 0);
        acc[1][n] = __builtin_amdgcn_mfma_f32_16x16x32_bf16(a1, W[s][n], acc[1][n], 0, 0, 0);
      }
    }
    // packed store: lane's 4 n-values -> 8 bytes at [v][b*64 + colL*4]
    {
      int vb = ft >> 4, b = ft & 15, v0 = vb * 32;
      #pragma unroll
      for (int mt = 0; mt < 2; ++mt)
        #pragma unroll
        for (int q = 0; q < 4; ++q){
          int v = v0 + mt * 16 + rg * 4 + q;
          unsigned lo = (unsigned)f2bf(acc[mt][0][q]) | ((unsigned)f2bf(acc[mt][1][q]) << 16);
          unsigned hi = (unsigned)f2bf(acc[mt][2][q]) | ((unsigned)f2bf(acc[mt][3][q]) << 16);
          uint2 pk = {lo, hi};
          *(uint2*)(yk + (size_t)v * ROW2 + b * 64 + colL * 4) = pk;
        }
    }
    __syncthreads();
  }
}

// dst[r] = alpha * (L @ src)[r] + addA[r] - (subB ? subB[r] : 0)    rows of 1024 bf16
// Sequential gather (one row at a time) — measured-best of {batched (R6),
// j-split (R8), XCD-sliced (R9)}. TLP covers the gather latency; effective
// gather throughput ~5.7 TB/s (random-access L3/HBM ceiling at 2KB granules).
__global__ void k_spmm2(const unsigned short* __restrict__ src,
                        const unsigned short* __restrict__ addA,
                        const unsigned short* __restrict__ subB,
                        unsigned short* __restrict__ dst,
                        const int* __restrict__ rp, const int* __restrict__ cols,
                        const float* __restrict__ vals, float alpha){
  int lane = threadIdx.x & 63;
  int r = blockIdx.x * 4 + (threadIdx.x >> 6);
  int j0 = lane * 16;
  float acc[16];
  #pragma unroll
  for (int p = 0; p < 16; ++p) acc[p] = 0.f;
  int beg = rp[r], end = rp[r + 1];
  for (int i = beg; i < end; ++i){
    float val = vals[i];
    int c = cols[i];
    const unsigned short* srow = src + (size_t)c * ROW2 + j0;
    short8 a0 = *(const short8*)srow;
    short8 a1 = *(const short8*)(srow + 8);
    #pragma unroll
    for (int p = 0; p < 8; ++p) acc[p]     += val * bf2f((unsigned short)a0[p]);
    #pragma unroll
    for (int p = 0; p < 8; ++p) acc[p + 8] += val * bf2f((unsigned short)a1[p]);
  }
  const unsigned short* arow = addA + (size_t)r * ROW2 + j0;
  short8 q0 = *(const short8*)arow;
  short8 q1 = *(const short8*)(arow + 8);
  #pragma unroll
  for (int p = 0; p < 8; ++p) acc[p]     = alpha * acc[p]     + bf2f((unsigned short)q0[p]);
  #pragma unroll
  for (int p = 0; p < 8; ++p) acc[p + 8] = alpha * acc[p + 8] + bf2f((unsigned short)q1[p]);
  if (subB){
    const unsigned short* brow = subB + (size_t)r * ROW2 + j0;
    short8 s0 = *(const short8*)brow;
    short8 s1 = *(const short8*)(brow + 8);
    #pragma unroll
    for (int p = 0; p < 8; ++p) acc[p]     -= bf2f((unsigned short)s0[p]);
    #pragma unroll
    for (int p = 0; p < 8; ++p) acc[p + 8] -= bf2f((unsigned short)s1[p]);
  }
  unsigned short* drow = dst + (size_t)r * ROW2 + j0;
  short8 o0, o1;
  #pragma unroll
  for (int p = 0; p < 8; ++p) o0[p] = (short)f2bf(acc[p]);
  #pragma unroll
  for (int p = 0; p < 8; ++p) o1[p] = (short)f2bf(acc[p + 8]);
  *(short8*)drow = o0;
  *(short8*)(drow + 8) = o1;
}

// out[b][v][o] = (L @ b1)[v][j] + y0[v][j] - b2[v][j] + bias[o]
// row layout: j = b*64 + colL*4 + n  <->  o = n*16 + colL  (un-permute on store)
__global__ void k_final(const unsigned short* __restrict__ src,   // b1
                        const unsigned short* __restrict__ y0,
                        const unsigned short* __restrict__ b2,
                        const float* __restrict__ bias,
                        float* __restrict__ out,
                        const int* __restrict__ rp, const int* __restrict__ cols,
                        const float* __restrict__ vals){
  int lane = threadIdx.x & 63;
  int v = blockIdx.x * 4 + (threadIdx.x >> 6);
  int j0 = lane * 16;
  float acc[16];
  #pragma unroll
  for (int p = 0; p < 16; ++p) acc[p] = 0.f;
  int beg = rp[v], end = rp[v + 1];
  for (int i = beg; i < end; ++i){
    float val = vals[i];
    int c = cols[i];
    const unsigned short* srow = src + (size_t)c * ROW2 + j0;
    short8 a0 = *(const short8*)srow;
    short8 a1 = *(const short8*)(srow + 8);
    #pragma unroll
    for (int p = 0; p < 8; ++p) acc[p]     += val * bf2f((unsigned short)a0[p]);
    #pragma unroll
    for (int p = 0; p < 8; ++p) acc[p + 8] += val * bf2f((unsigned short)a1[p]);
  }
  const unsigned short* yrow = y0 + (size_t)v * ROW2 + j0;
  const unsigned short* brow = b2 + (size_t)v * ROW2 + j0;
  short8 q0 = *(const short8*)yrow;
  short8 q1 = *(const short8*)(yrow + 8);
  short8 s0 = *(const short8*)brow;
  short8 s1 = *(const short8*)(brow + 8);
  #pragma unroll
  for (int p = 0; p < 8; ++p) acc[p]     += bf2f((unsigned short)q0[p]) - bf2f((unsigned short)s0[p]);
  #pragma unroll
  for (int p = 0; p < 8; ++p) acc[p + 8] += bf2f((unsigned short)q1[p]) - bf2f((unsigned short)s1[p]);
  // j = j0+p ; b = lane>>2 ; c0 = (lane&3)*4 ; p = q*4+n -> o = n*16 + c0 + q
  int b = lane >> 2;
  int c0 = (lane & 3) * 4;
  float* obase = out + ((size_t)b * V_N + v) * FOUT;
  #pragma unroll
  for (int n = 0; n < 4; ++n){
    float4 bv = *(const float4*)(bias + n * 16 + c0);
    float4 w;
    w.x = acc[0 * 4 + n] + bv.x;
    w.y = acc[1 * 4 + n] + bv.y;
    w.z = acc[2 * 4 + n] + bv.z;
    w.w = acc[3 * 4 + n] + bv.w;
    *(float4*)(obase + n * 16 + c0) = w;
  }
}

extern "C" void kernel_launch(void* const* d_in, const int* in_sizes, int n_in,
                              void* d_out, int out_size, void* d_ws, size_t ws_size,
                              hipStream_t stream) {
  const float* inputs   = (const float*)d_in[0];
  const float* weight   = (const float*)d_in[1];
  const float* bias     = (const float*)d_in[2];
  const float* lap_vals = (const float*)d_in[3];
  const int*   lap_rows = (const int*)d_in[4];
  const int*   lap_cols = (const int*)d_in[5];
  float* out = (float*)d_out;
  int nnz = in_sizes[3];

  char* ws = (char*)d_ws;
  size_t off = 0;
  auto alloc = [&](size_t bytes) -> void* {
    void* p = ws + off;
    off += (bytes + 255) & ~(size_t)255;
    return p;
  };
  const size_t YB = (size_t)V_N * ROW2 * 2;   // 24 MiB
  unsigned short* y0 = (unsigned short*)alloc(YB);
  unsigned short* y1 = (unsigned short*)alloc(YB);
  unsigned short* y2 = (unsigned short*)alloc(YB);
  unsigned short* y3 = (unsigned short*)alloc(YB);
  unsigned short* c2 = (unsigned short*)alloc(YB);   // clenshaw b2
  unsigned short* c1 = (unsigned short*)alloc(YB);   // clenshaw b1
  unsigned short* wb = (unsigned short*)alloc(65536 * 2);
  int*   cnt   = (int*)alloc(V_N * 4);
  int*   cur   = (int*)alloc(V_N * 4);
  int*   rp    = (int*)alloc((V_N + 1) * 4);
  int*   colss = (int*)alloc((size_t)nnz * 4);
  float* valss = (float*)alloc((size_t)nnz * 4);

  // CSR build
  k_zero<<<(2 * V_N + 255) / 256, 256, 0, stream>>>(cnt, 2 * V_N);
  k_hist<<<(nnz + 255) / 256, 256, 0, stream>>>(lap_rows, cnt, nnz);
  k_scan<<<1, 256, 0, stream>>>(cnt, rp);
  k_scatter<<<(nnz + 255) / 256, 256, 0, stream>>>(lap_rows, lap_cols, lap_vals, rp, cur,
                                                   colss, valss, nnz);
  // weight fragments + projection y_k = X0 @ W_k
  k_convw<<<65536 / 256, 256, 0, stream>>>(weight, wb);
  k_proj<<<(V_N / 32) * B_N / TPB_TILES, 256, 0, stream>>>(inputs, wb, y0, y1, y2, y3);

  // Clenshaw: b2 = y2 + 2 L y3 ; b1 = y1 + 2 L b2 - y3 ; out = y0 + L b1 - b2 + bias
  k_spmm2<<<V_N / 4, 256, 0, stream>>>(y3, y2, nullptr, c2, rp, colss, valss, 2.0f);
  k_spmm2<<<V_N / 4, 256, 0, stream>>>(c2, y1, y3, c1, rp, colss, valss, 2.0f);
  k_final<<<V_N / 4, 256, 0, stream>>>(c1, y0, c2, bias, out, rp, colss, valss);
}